// Round 3
// baseline (431.103 us; speedup 1.0000x reference)
//
#include <hip/hip_runtime.h>
#include <cstdint>

// ---------------------------------------------------------------------------
// SelfAttention (QK-l2norm variant), MI355X/gfx950.
// R3: projection GEMMs -> 256x256 8-wave counted-vmcnt pipeline (BK=32,
// 128KB dynamic LDS, vmcnt(8) never drains to 0 in the main loop).
// Attention: swapped-operand flash kernel (unchanged from R2).
// Projections: Markidis hi/lo bf16 split (3 MFMAs) ~ fp32-accurate.
// ---------------------------------------------------------------------------

typedef __bf16 bfx8 __attribute__((ext_vector_type(8)));
typedef __bf16 bfx4 __attribute__((ext_vector_type(4)));
typedef float  f32x4 __attribute__((ext_vector_type(4)));

#define NB   4
#define NH   16
#define SEQ  2048
#define CH   1024
#define DD   64
#define MROWS (NB*SEQ)             /* 8192 */
#define BHLD  (NB*NH*SEQ*DD)       /* 8388608 */

__device__ __forceinline__ void async16(void* lds, const void* g) {
  __builtin_amdgcn_global_load_lds((const __attribute__((address_space(1))) void*)g,
                                   (__attribute__((address_space(3))) void*)lds, 16, 0, 0);
}
__device__ __forceinline__ f32x4 mfma16(bfx8 a, bfx8 b, f32x4 c) {
  return __builtin_amdgcn_mfma_f32_16x16x32_bf16(a, b, c, 0, 0, 0);
}

// --------------------------- hi/lo split (Markidis) -------------------------
__global__ __launch_bounds__(256) void split_kernel(const float4* __restrict__ src,
                                                    __bf16* __restrict__ hi,
                                                    __bf16* __restrict__ lo, int n4) {
  int i = blockIdx.x * 256 + threadIdx.x;
  if (i >= n4) return;
  float4 v = src[i];
  float vv[4] = {v.x, v.y, v.z, v.w};
  bfx4 h, l;
  #pragma unroll
  for (int j = 0; j < 4; ++j) {
    __bf16 hb = (__bf16)vv[j];
    h[j] = hb;
    l[j] = (__bf16)(vv[j] - (float)hb);
  }
  *(bfx4*)(hi + 4*(size_t)i) = h;
  *(bfx4*)(lo + 4*(size_t)i) = l;
}

// --------------------------- bias nonzero scan ------------------------------
__global__ __launch_bounds__(256) void scan_nz(const uint4* __restrict__ p, int n4,
                                               int* __restrict__ flag) {
  unsigned acc = 0;
  const int stride = gridDim.x * 256;
  for (int i = blockIdx.x * 256 + threadIdx.x; i < n4; i += stride) {
    uint4 u = p[i];
    acc |= (u.x | u.y | u.z | u.w) & 0x7fffffffu;
  }
  if (acc) atomicOr(flag, 1);
}

// --------------------- split-bf16 GEMM 256x256 (NT, pipelined) --------------
// C[M,N] = A[M,K]*B[N,K]^T, hi/lo bf16 pairs. 8 waves (2M x 4N), BK=32.
// LDS: 2 bufs x {Ah,Al,Bh,Bl}[256x32] = 131072 B (dynamic).
// Pipeline: at tile top issue 8 global_load_lds for t+1, then vmcnt(8)
// (waits only tile t's loads; ~1 tile of slack), raw s_barrier (no drain).
// EPI==1: +concat(q_bias,0,v_bias); q/k -> [B,H,L,D] bf16, v -> [B,H,D,L].
// EPI==2: +proj_b -> f32 out.
template<int EPI>
__global__ __launch_bounds__(512, 2) void gemm256(
    const __bf16* __restrict__ Agh, const __bf16* __restrict__ Agl,
    const __bf16* __restrict__ Bgh, const __bf16* __restrict__ Bgl,
    const int Ntiles, const int K,
    const float* __restrict__ biasA, const float* __restrict__ biasB,
    float* __restrict__ outF, __bf16* __restrict__ outQ, __bf16* __restrict__ outV)
{
  extern __shared__ __align__(16) char lds[];   // 131072
  const int tid = threadIdx.x;
  const int lane = tid & 63, w = tid >> 6;
  const int l15 = lane & 15, l4 = lane >> 4;
  const int nwg = (int)gridDim.x;
  const int wk = (int)(blockIdx.x & 7) * (nwg >> 3) + (int)(blockIdx.x >> 3); // nwg%8==0
  const int mt = wk / Ntiles, nt = wk % Ntiles;
  const int m0 = mt * 256, n0 = nt * 256;
  const int wm = w >> 2, wn = w & 3;          // 2 x 4 wave grid

  const f32x4 zz = {0.f, 0.f, 0.f, 0.f};
  f32x4 acc[8][4];
  #pragma unroll
  for (int a = 0; a < 8; ++a)
    #pragma unroll
    for (int b = 0; b < 4; ++b) acc[a][b] = zz;

  // staging: per operand 2 loads/thread; slot s = i*512+tid -> lds byte s*16,
  // row = s>>2 (global-tile row), phys chunk = s&3, logical chunk = (s&3)^((row>>1)&3)
  const int st_row[2] = { tid >> 2, 128 + (tid >> 2) };
  const int st_c[2]   = { (tid & 3) ^ ((st_row[0] >> 1) & 3),
                          (tid & 3) ^ ((st_row[1] >> 1) & 3) };
  const int st_lds[2] = { (0*512 + w*64) * 16, (1*512 + w*64) * 16 };

  const int NT = K >> 5;
  auto stage = [&](int kt, int buf) {
    const int kc = kt << 5;
    char* bb = lds + buf * 65536;
    #pragma unroll
    for (int i = 0; i < 2; ++i) {
      const size_t ga = (size_t)(m0 + st_row[i]) * K + (size_t)(kc + st_c[i]*8);
      const size_t gb = (size_t)(n0 + st_row[i]) * K + (size_t)(kc + st_c[i]*8);
      async16(bb +         st_lds[i], Agh + ga);
      async16(bb + 16384 + st_lds[i], Agl + ga);
      async16(bb + 32768 + st_lds[i], Bgh + gb);
      async16(bb + 49152 + st_lds[i], Bgl + gb);
    }
  };

  stage(0, 0);
  for (int t = 0; t < NT; ++t) {
    const int cur = t & 1;
    char* bc = lds + cur * 65536;
    const int tn = (t + 1 < NT) ? (t + 1) : (NT - 1);   // last iter: redundant reload
    stage(tn, cur ^ 1);
    asm volatile("s_waitcnt vmcnt(8)" ::: "memory");    // tile t's loads complete
    __builtin_amdgcn_s_barrier();                       // all waves' loads visible
    asm volatile("" ::: "memory");

    // B fragments: held in regs for the whole tile (8 x b128)
    bfx8 bh[4], bl[4];
    #pragma unroll
    for (int nf = 0; nf < 4; ++nf) {
      const int r = wn*64 + nf*16 + l15;
      const int off = r*64 + ((l4 ^ ((r >> 1) & 3)) * 16);
      bh[nf] = *(const bfx8*)(bc + 32768 + off);
      bl[nf] = *(const bfx8*)(bc + 49152 + off);
    }
    #pragma unroll
    for (int mh = 0; mh < 2; ++mh) {
      bfx8 ah[4], al[4];
      #pragma unroll
      for (int f = 0; f < 4; ++f) {
        const int r = wm*128 + mh*64 + f*16 + l15;
        const int off = r*64 + ((l4 ^ ((r >> 1) & 3)) * 16);
        ah[f] = *(const bfx8*)(bc + off);
        al[f] = *(const bfx8*)(bc + 16384 + off);
      }
      __builtin_amdgcn_s_setprio(1);
      #pragma unroll
      for (int f = 0; f < 4; ++f)
        #pragma unroll
        for (int nf = 0; nf < 4; ++nf) {
          acc[mh*4+f][nf] = mfma16(al[f], bh[nf], acc[mh*4+f][nf]);
          acc[mh*4+f][nf] = mfma16(ah[f], bl[nf], acc[mh*4+f][nf]);
          acc[mh*4+f][nf] = mfma16(ah[f], bh[nf], acc[mh*4+f][nf]);
        }
      __builtin_amdgcn_s_setprio(0);
    }
    asm volatile("" ::: "memory");
    __builtin_amdgcn_s_barrier();                       // buf cur free for t+2
  }

  // epilogue: C/D layout col=lane&15, row=4*(lane>>4)+reg
  #pragma unroll
  for (int mf = 0; mf < 8; ++mf)
    #pragma unroll
    for (int nf = 0; nf < 4; ++nf)
      #pragma unroll
      for (int rg = 0; rg < 4; ++rg) {
        const int gr = m0 + wm*128 + mf*16 + 4*l4 + rg;
        const int gc = n0 + wn*64 + nf*16 + l15;
        float v = acc[mf][nf][rg];
        if (EPI == 1) {
          v += (gc < CH) ? biasA[gc] : ((gc >= 2*CH) ? biasB[gc - 2*CH] : 0.f);
          const int which = gc >> 10, cc = gc & (CH-1);
          const int hh = cc >> 6, dd = cc & 63;
          const int bb = gr >> 11, ll = gr & (SEQ-1);
          if (which < 2)
            outQ[(size_t)which*BHLD + ((size_t)((bb*NH + hh)*SEQ) + ll)*DD + dd] = (__bf16)v;
          else
            outV[((size_t)(bb*NH + hh)*DD + dd)*SEQ + ll] = (__bf16)v;
        } else {
          outF[(size_t)gr*CH + gc] = v + biasA[gc];
        }
      }
}

// --------------------------- l2 normalize q,k (in place) --------------------
__global__ __launch_bounds__(256) void norml2(__bf16* __restrict__ qk,
                                              const float* __restrict__ scale_mul) {
  const int tid = threadIdx.x;
  const int rid = blockIdx.x * 32 + (tid >> 3);
  const int e0 = (tid & 7) * 8;
  const int r = rid & (131072 - 1);
  const bool isq = rid < 131072;
  const int hh = (r >> 11) & 15;
  float sm = 1.f;
  if (isq) sm = __expf(fminf(scale_mul[hh], 4.605170185988091f));
  __bf16* p = qk + (size_t)rid * DD + e0;
  bfx8 v = *(bfx8*)p;
  float f[8]; float ss = 0.f;
  #pragma unroll
  for (int j = 0; j < 8; ++j) { f[j] = (float)v[j]; ss += f[j]*f[j]; }
  ss += __shfl_xor(ss, 1); ss += __shfl_xor(ss, 2); ss += __shfl_xor(ss, 4);
  const float sc = sm / fmaxf(sqrtf(ss), 1e-12f);
  #pragma unroll
  for (int j = 0; j < 8; ++j) v[j] = (__bf16)(f[j] * sc);
  *(bfx8*)p = v;
}

// --------------------------- flash attention (bf16, swapped ops) ------------
__global__ __launch_bounds__(256, 2) void attn_kernel(
    const __bf16* __restrict__ qn, const __bf16* __restrict__ kn,
    const __bf16* __restrict__ vtg,
    const float* __restrict__ bias, const int* __restrict__ flag,
    __bf16* __restrict__ ao_hi, __bf16* __restrict__ ao_lo)
{
  __shared__ alignas(16) char Ks[16384];
  __shared__ alignas(16) char Vt[16384];
  __shared__ alignas(16) char Ps[32768];

  const int tid = threadIdx.x, lane = tid & 63, w = tid >> 6;
  const int l15 = lane & 15, l4 = lane >> 4;
  const int wk = (int)(blockIdx.x & 7) * 128 + (int)(blockIdx.x >> 3);
  const int qt = wk & 15, h = (wk >> 4) & 15, b = wk >> 8;
  const size_t bh = ((size_t)(b*NH + h)) * SEQ * DD;
  const int hasbias = *flag;
  char* Pw = Ps + w*8192;

  bfx8 Qf[2][2];
  const int q0 = qt*128 + w*32;
  #pragma unroll
  for (int mf = 0; mf < 2; ++mf)
    #pragma unroll
    for (int kd = 0; kd < 2; ++kd)
      Qf[mf][kd] = *(const bfx8*)(qn + bh + (size_t)(q0 + mf*16 + l15)*DD + kd*32 + l4*8);

  const f32x4 zz = {0.f, 0.f, 0.f, 0.f};
  f32x4 O[2][4];
  float m_[2] = {-1e30f, -1e30f}, l_[2] = {0.f, 0.f};
  #pragma unroll
  for (int mf = 0; mf < 2; ++mf)
    #pragma unroll
    for (int nd = 0; nd < 4; ++nd) O[mf][nd] = zz;

  for (int t = 0; t < 16; ++t) {
    __syncthreads();

    const __bf16* ksrc = kn + bh + (size_t)t*128*DD;
    #pragma unroll
    for (int i = 0; i < 4; ++i) {
      const int s = i*256 + tid;
      const int row = s >> 3;
      const int c = (s & 7) ^ (row & 7);
      async16(Ks + (size_t)(i*256 + w*64)*16, ksrc + (size_t)row*DD + c*8);
    }
    const __bf16* vsrc = vtg + bh + (size_t)t*128;
    #pragma unroll
    for (int i = 0; i < 4; ++i) {
      const int s = i*256 + tid;
      const int row = s >> 4;
      const int c = (s & 15) ^ (row & 15);
      async16(Vt + (size_t)(i*256 + w*64)*16, vsrc + (size_t)row*SEQ + c*8);
    }
    __syncthreads();

    // ---- S^T = K Q^T : lane holds q=l15(+16mf), k=16nf+4*l4+rg ----
    f32x4 ST[2][8];
    __builtin_amdgcn_s_setprio(1);
    #pragma unroll
    for (int nf = 0; nf < 8; ++nf) {
      const int r = nf*16 + l15;
      const bfx8 K0 = *(const bfx8*)(Ks + r*128 + ((l4 ^ (r & 7)) * 16));
      const bfx8 K1 = *(const bfx8*)(Ks + r*128 + (((4 + l4) ^ (r & 7)) * 16));
      #pragma unroll
      for (int mf = 0; mf < 2; ++mf) {
        f32x4 sacc = mfma16(K0, Qf[mf][0], zz);
        ST[mf][nf] = mfma16(K1, Qf[mf][1], sacc);
      }
    }
    __builtin_amdgcn_s_setprio(0);

    if (hasbias) {
      #pragma unroll
      for (int mf = 0; mf < 2; ++mf) {
        const size_t qg = (size_t)(q0 + mf*16 + l15);
        const float* bp = bias + qg*SEQ + (size_t)t*128;
        #pragma unroll
        for (int nf = 0; nf < 8; ++nf)
          #pragma unroll
          for (int rg = 0; rg < 4; ++rg)
            ST[mf][nf][rg] += bp[nf*16 + 4*l4 + rg];
      }
    }

    #pragma unroll
    for (int mf = 0; mf < 2; ++mf) {
      f32x4 mv = ST[mf][0];
      #pragma unroll
      for (int nf = 1; nf < 8; ++nf)
        #pragma unroll
        for (int rg = 0; rg < 4; ++rg) mv[rg] = fmaxf(mv[rg], ST[mf][nf][rg]);
      float mx = fmaxf(fmaxf(mv[0], mv[1]), fmaxf(mv[2], mv[3]));
      mx = fmaxf(mx, __shfl_xor(mx, 16));
      mx = fmaxf(mx, __shfl_xor(mx, 32));
      const float mn = fmaxf(m_[mf], mx);
      const float corr = __expf(m_[mf] - mn);
      f32x4 sv = zz;
      #pragma unroll
      for (int nf = 0; nf < 8; ++nf) {
        #pragma unroll
        for (int rg = 0; rg < 4; ++rg) {
          ST[mf][nf][rg] = __expf(ST[mf][nf][rg] - mn);
          sv[rg] += ST[mf][nf][rg];
        }
      }
      float rs = (sv[0] + sv[1]) + (sv[2] + sv[3]);
      rs += __shfl_xor(rs, 16);
      rs += __shfl_xor(rs, 32);
      l_[mf] = l_[mf] * corr + rs;
      m_[mf] = mn;
      #pragma unroll
      for (int nd = 0; nd < 4; ++nd)
        #pragma unroll
        for (int rg = 0; rg < 4; ++rg) O[mf][nd][rg] *= corr;

      const int row = mf*16 + l15;
      #pragma unroll
      for (int nf = 0; nf < 8; ++nf) {
        bfx4 p4;
        #pragma unroll
        for (int rg = 0; rg < 4; ++rg) p4[rg] = (__bf16)ST[mf][nf][rg];
        const int cpos = (2*nf + (l4 >> 1)) ^ l15;
        *(bfx4*)(Pw + row*256 + cpos*16 + (l4 & 1)*8) = p4;
      }
    }

    __builtin_amdgcn_s_setprio(1);
    #pragma unroll
    for (int kk = 0; kk < 4; ++kk) {
      bfx8 Pf[2];
      #pragma unroll
      for (int mf = 0; mf < 2; ++mf)
        Pf[mf] = *(const bfx8*)(Pw + (mf*16 + l15)*256 + (((4*kk + l4) ^ l15) * 16));
      #pragma unroll
      for (int nd = 0; nd < 4; ++nd) {
        const bfx8 Vf = *(const bfx8*)(Vt + (nd*16 + l15)*256 + (((4*kk + l4) ^ l15) * 16));
        #pragma unroll
        for (int mf = 0; mf < 2; ++mf)
          O[mf][nd] = mfma16(Vf, Pf[mf], O[mf][nd]);
      }
    }
    __builtin_amdgcn_s_setprio(0);
  }

  #pragma unroll
  for (int mf = 0; mf < 2; ++mf) {
    const float inv = 1.f / l_[mf];
    const int qg = q0 + mf*16 + l15;
    #pragma unroll
    for (int nd = 0; nd < 4; ++nd) {
      bfx4 hb, lb;
      #pragma unroll
      for (int rg = 0; rg < 4; ++rg) {
        const float v = O[mf][nd][rg] * inv;
        hb[rg] = (__bf16)v;
        lb[rg] = (__bf16)(v - (float)hb[rg]);
      }
      const size_t idx = ((size_t)(b*SEQ + qg))*CH + h*DD + nd*16 + 4*l4;
      *(bfx4*)(ao_hi + idx) = hb;
      *(bfx4*)(ao_lo + idx) = lb;
    }
  }
}

// ---------------------------------------------------------------------------
extern "C" void kernel_launch(void* const* d_in, const int* in_sizes, int n_in,
                              void* d_out, int out_size, void* d_ws, size_t ws_size,
                              hipStream_t stream) {
  const float* x         = (const float*)d_in[0];
  const float* attn_bias = (const float*)d_in[1];
  const float* qkv_w     = (const float*)d_in[2];
  const float* q_bias    = (const float*)d_in[3];
  const float* v_bias    = (const float*)d_in[4];
  const float* scale_mul = (const float*)d_in[5];
  const float* proj_w    = (const float*)d_in[6];
  const float* proj_b    = (const float*)d_in[7];
  float* out = (float*)d_out;

  char* ws = (char*)d_ws;
  size_t off = 0;
  auto alloc = [&](size_t n) { char* p = ws + off; off += (n + 255) & ~(size_t)255; return p; };
  __bf16* x_h  = (__bf16*)alloc((size_t)MROWS*CH*2);
  __bf16* x_l  = (__bf16*)alloc((size_t)MROWS*CH*2);
  __bf16* w_h  = (__bf16*)alloc((size_t)3*CH*CH*2);
  __bf16* w_l  = (__bf16*)alloc((size_t)3*CH*CH*2);
  __bf16* p_h  = (__bf16*)alloc((size_t)CH*CH*2);
  __bf16* p_l  = (__bf16*)alloc((size_t)CH*CH*2);
  __bf16* qkvn = (__bf16*)alloc((size_t)2*BHLD*2);   // q,k [B,H,L,D]
  __bf16* vt   = (__bf16*)alloc((size_t)BHLD*2);     // v   [B,H,D,L]
  __bf16* ao_h = (__bf16*)alloc((size_t)MROWS*CH*2);
  __bf16* ao_l = (__bf16*)alloc((size_t)MROWS*CH*2);
  int*    flag = (int*)alloc(256);

  (void)hipFuncSetAttribute(reinterpret_cast<const void*>(&gemm256<1>),
                            hipFuncAttributeMaxDynamicSharedMemorySize, 131072);
  (void)hipFuncSetAttribute(reinterpret_cast<const void*>(&gemm256<2>),
                            hipFuncAttributeMaxDynamicSharedMemorySize, 131072);

  split_kernel<<<MROWS*CH/4/256, 256, 0, stream>>>((const float4*)x, x_h, x_l, MROWS*CH/4);
  split_kernel<<<3*CH*CH/4/256, 256, 0, stream>>>((const float4*)qkv_w, w_h, w_l, 3*CH*CH/4);
  split_kernel<<<CH*CH/4/256, 256, 0, stream>>>((const float4*)proj_w, p_h, p_l, CH*CH/4);

  hipMemsetAsync(flag, 0, sizeof(int), stream);
  scan_nz<<<2048, 256, 0, stream>>>((const uint4*)attn_bias, SEQ*SEQ/4, flag);

  // GEMM1: [8192,3072] = x * qkv_w^T (+bias) -> q/k [B,H,L,D], v [B,H,D,L]
  gemm256<1><<<(MROWS/256)*(3*CH/256), 512, 131072, stream>>>(
      x_h, x_l, w_h, w_l, 3*CH/256, CH, q_bias, v_bias, nullptr, qkvn, vt);

  norml2<<<2*NB*NH*SEQ/32, 256, 0, stream>>>(qkvn, scale_mul);

  attn_kernel<<<NB*NH*(SEQ/128), 256, 0, stream>>>(
      qkvn, qkvn + (size_t)BHLD, vt, attn_bias, flag, ao_h, ao_l);

  // GEMM2: d_out = attn_out * proj_w^T + proj_b
  gemm256<2><<<(MROWS/256)*(CH/256), 512, 131072, stream>>>(
      ao_h, ao_l, p_h, p_l, CH/256, CH, proj_b, nullptr, out, nullptr, nullptr);
}

// Round 4
// 390.587 us; speedup vs baseline: 1.1037x; 1.1037x over previous
//
#include <hip/hip_runtime.h>
#include <cstdint>

// ---------------------------------------------------------------------------
// SelfAttention (QK-l2norm variant), MI355X/gfx950.
// R4: projection GEMMs -> 256x128-tile, BK=32, 8-wave, 3-slot LDS rotation,
// m201-style per-phase interleave {ds_read || global_load_lds || MFMA} with
// counted vmcnt(6) (never drains in steady state). Grid 768/256 blocks (no tail).
// Attention: swapped-operand flash kernel (R2). Markidis hi/lo split numerics.
// ---------------------------------------------------------------------------

typedef __bf16 bfx8 __attribute__((ext_vector_type(8)));
typedef __bf16 bfx4 __attribute__((ext_vector_type(4)));
typedef float  f32x4 __attribute__((ext_vector_type(4)));

#define NB   4
#define NH   16
#define SEQ  2048
#define CH   1024
#define DD   64
#define MROWS (NB*SEQ)             /* 8192 */
#define BHLD  (NB*NH*SEQ*DD)       /* 8388608 */
#define SLOT  49152                /* Ah16K | Al16K | Bh8K | Bl8K */

__device__ __forceinline__ void async16(void* lds, const void* g) {
  __builtin_amdgcn_global_load_lds((const __attribute__((address_space(1))) void*)g,
                                   (__attribute__((address_space(3))) void*)lds, 16, 0, 0);
}
__device__ __forceinline__ f32x4 mfma16(bfx8 a, bfx8 b, f32x4 c) {
  return __builtin_amdgcn_mfma_f32_16x16x32_bf16(a, b, c, 0, 0, 0);
}

// --------------------------- hi/lo split (Markidis) -------------------------
__global__ __launch_bounds__(256) void split_kernel(const float4* __restrict__ src,
                                                    __bf16* __restrict__ hi,
                                                    __bf16* __restrict__ lo, int n4) {
  int i = blockIdx.x * 256 + threadIdx.x;
  if (i >= n4) return;
  float4 v = src[i];
  float vv[4] = {v.x, v.y, v.z, v.w};
  bfx4 h, l;
  #pragma unroll
  for (int j = 0; j < 4; ++j) {
    __bf16 hb = (__bf16)vv[j];
    h[j] = hb;
    l[j] = (__bf16)(vv[j] - (float)hb);
  }
  *(bfx4*)(hi + 4*(size_t)i) = h;
  *(bfx4*)(lo + 4*(size_t)i) = l;
}

// --------------------------- bias nonzero scan ------------------------------
__global__ __launch_bounds__(256) void scan_nz(const uint4* __restrict__ p, int n4,
                                               int* __restrict__ flag) {
  unsigned acc = 0;
  const int stride = gridDim.x * 256;
  for (int i = blockIdx.x * 256 + threadIdx.x; i < n4; i += stride) {
    uint4 u = p[i];
    acc |= (u.x | u.y | u.z | u.w) & 0x7fffffffu;
  }
  if (acc) atomicOr(flag, 1);
}

// ------------------- split-bf16 GEMM 256x128, 8-phase pipelined -------------
// C[M,N] = A[M,K]*B[N,K]^T, K=1024. hi/lo bf16 pairs. 8 waves 4M x 2N,
// per-wave 64x64, BK=32, 32 K-tiles. LDS = 3 slots x 48KB (tile i in slot i%3).
// Per K-tile 2 phases; phase = {ds_read frags; stage 3 loads for tile i+2;
// vmcnt(6); barrier; 24 MFMA; barrier}. vmcnt(6) = loads of 2 newest phases
// allowed in flight; certifies tile i fully staged before its reads.
// EPI==1: +concat(q_bias,0,v_bias); q/k -> [B,H,L,D] bf16, v -> [B,H,D,L].
// EPI==2: +proj_b -> f32 out.
template<int EPI>
__global__ __launch_bounds__(512, 2) void gemmp(
    const __bf16* __restrict__ Agh, const __bf16* __restrict__ Agl,
    const __bf16* __restrict__ Bgh, const __bf16* __restrict__ Bgl,
    const int Ntiles,
    const float* __restrict__ biasA, const float* __restrict__ biasB,
    float* __restrict__ outF, __bf16* __restrict__ outQ, __bf16* __restrict__ outV)
{
  extern __shared__ __align__(16) char lds[];   // 3*49152 = 147456
  const int tid = threadIdx.x;
  const int lane = tid & 63, w = tid >> 6;
  const int l15 = lane & 15, l4 = lane >> 4;
  const int nwg = (int)gridDim.x;
  const int wk = (int)(blockIdx.x & 7) * (nwg >> 3) + (int)(blockIdx.x >> 3); // nwg%8==0
  const int mt = wk / Ntiles, nt = wk % Ntiles;
  const int m0 = mt * 256, n0 = nt * 128;
  const int wm = w >> 1, wn = w & 1;            // 4M x 2N wave grid

  const f32x4 zz = {0.f, 0.f, 0.f, 0.f};
  f32x4 acc[4][4];
  #pragma unroll
  for (int a = 0; a < 4; ++a)
    #pragma unroll
    for (int b = 0; b < 4; ++b) acc[a][b] = zz;

  // ---- staging geometry (pre-swizzled global source; linear LDS dest) ----
  // A: 256 rows x 4 chunks(16B) = 1024 slots = 2 units; B: 128 rows = 512 slots.
  const int rA0 = tid >> 2, rA1 = 128 + (tid >> 2), rB = tid >> 2;
  const int cA0 = (tid & 3) ^ ((rA0 >> 1) & 3);
  const int cA1 = (tid & 3) ^ ((rA1 >> 1) & 3);
  const int cB  = (tid & 3) ^ ((rB  >> 1) & 3);
  const size_t aofs0 = (size_t)(m0 + rA0) * 1024 + cA0 * 8;
  const size_t aofs1 = (size_t)(m0 + rA1) * 1024 + cA1 * 8;
  const size_t bofs  = (size_t)(n0 + rB ) * 1024 + cB  * 8;
  const int wlds = w * 1024;                    // wave-uniform; HW adds lane*16

  auto stageH = [&](int kt, int sl, int half) {
    char* sb = lds + sl * SLOT;
    const int kc = kt << 5;
    if (half == 0) {
      async16(sb +         wlds, Agh + aofs0 + kc);
      async16(sb +  8192 + wlds, Agh + aofs1 + kc);
      async16(sb + 16384 + wlds, Agl + aofs0 + kc);
    } else {
      async16(sb + 24576 + wlds, Agl + aofs1 + kc);
      async16(sb + 32768 + wlds, Bgh + bofs + kc);
      async16(sb + 40960 + wlds, Bgl + bofs + kc);
    }
  };

  // fragment LDS offsets (swizzle matches staging involution)
  auto offA = [&](int f) { const int r = wm*64 + f*16 + l15;
                           return r*64 + ((l4 ^ ((r >> 1) & 3)) * 16); };
  auto offB = [&](int nf) { const int r = wn*64 + nf*16 + l15;
                            return r*64 + ((l4 ^ ((r >> 1) & 3)) * 16); };

  bfx8 bh[4], bl[4];

  // ---- prologue: tiles 0,1 -> slots 0,1; certify tile 0 ----
  stageH(0, 0, 0); stageH(0, 0, 1);
  stageH(1, 1, 0); stageH(1, 1, 1);
  asm volatile("s_waitcnt vmcnt(6)" ::: "memory");
  __builtin_amdgcn_s_barrier();

  int sl = 0, s2 = 2;
  #pragma unroll 1
  for (int i = 0; i < 30; ++i) {
    char* bc = lds + sl * SLOT;
    // ---- even phase: B frags + A-half0, stage half0 of tile i+2 ----
    bfx8 a0h[2], a0l[2];
    #pragma unroll
    for (int nf = 0; nf < 4; ++nf) {
      const int o = offB(nf);
      bh[nf] = *(const bfx8*)(bc + 32768 + o);
      bl[nf] = *(const bfx8*)(bc + 40960 + o);
    }
    #pragma unroll
    for (int f = 0; f < 2; ++f) {
      const int o = offA(f);
      a0h[f] = *(const bfx8*)(bc + o);
      a0l[f] = *(const bfx8*)(bc + 16384 + o);
    }
    stageH(i + 2, s2, 0);
    asm volatile("s_waitcnt vmcnt(6)" ::: "memory");
    __builtin_amdgcn_s_barrier();
    __builtin_amdgcn_s_setprio(1);
    #pragma unroll
    for (int f = 0; f < 2; ++f)
      #pragma unroll
      for (int nf = 0; nf < 4; ++nf) {
        acc[f][nf] = mfma16(a0l[f], bh[nf], acc[f][nf]);
        acc[f][nf] = mfma16(a0h[f], bl[nf], acc[f][nf]);
        acc[f][nf] = mfma16(a0h[f], bh[nf], acc[f][nf]);
      }
    __builtin_amdgcn_s_setprio(0);
    __builtin_amdgcn_s_barrier();

    // ---- odd phase: A-half1, stage half1 of tile i+2 ----
    bfx8 a1h[2], a1l[2];
    #pragma unroll
    for (int f = 0; f < 2; ++f) {
      const int o = offA(2 + f);
      a1h[f] = *(const bfx8*)(bc + o);
      a1l[f] = *(const bfx8*)(bc + 16384 + o);
    }
    stageH(i + 2, s2, 1);
    asm volatile("s_waitcnt vmcnt(6)" ::: "memory");
    __builtin_amdgcn_s_barrier();
    __builtin_amdgcn_s_setprio(1);
    #pragma unroll
    for (int f = 0; f < 2; ++f)
      #pragma unroll
      for (int nf = 0; nf < 4; ++nf) {
        acc[2+f][nf] = mfma16(a1l[f], bh[nf], acc[2+f][nf]);
        acc[2+f][nf] = mfma16(a1h[f], bl[nf], acc[2+f][nf]);
        acc[2+f][nf] = mfma16(a1h[f], bh[nf], acc[2+f][nf]);
      }
    __builtin_amdgcn_s_setprio(0);
    __builtin_amdgcn_s_barrier();

    sl = (sl == 2) ? 0 : sl + 1;
    s2 = (s2 == 2) ? 0 : s2 + 1;
  }

  // ---- tail: tiles 30, 31 (no staging; shrinking vmcnt) ----
  #pragma unroll 1
  for (int i = 30; i < 32; ++i) {
    char* bc = lds + sl * SLOT;
    bfx8 a0h[2], a0l[2];
    #pragma unroll
    for (int nf = 0; nf < 4; ++nf) {
      const int o = offB(nf);
      bh[nf] = *(const bfx8*)(bc + 32768 + o);
      bl[nf] = *(const bfx8*)(bc + 40960 + o);
    }
    #pragma unroll
    for (int f = 0; f < 2; ++f) {
      const int o = offA(f);
      a0h[f] = *(const bfx8*)(bc + o);
      a0l[f] = *(const bfx8*)(bc + 16384 + o);
    }
    if (i == 30) asm volatile("s_waitcnt vmcnt(3)" ::: "memory");
    __builtin_amdgcn_s_barrier();
    __builtin_amdgcn_s_setprio(1);
    #pragma unroll
    for (int f = 0; f < 2; ++f)
      #pragma unroll
      for (int nf = 0; nf < 4; ++nf) {
        acc[f][nf] = mfma16(a0l[f], bh[nf], acc[f][nf]);
        acc[f][nf] = mfma16(a0h[f], bl[nf], acc[f][nf]);
        acc[f][nf] = mfma16(a0h[f], bh[nf], acc[f][nf]);
      }
    __builtin_amdgcn_s_setprio(0);
    __builtin_amdgcn_s_barrier();

    bfx8 a1h[2], a1l[2];
    #pragma unroll
    for (int f = 0; f < 2; ++f) {
      const int o = offA(2 + f);
      a1h[f] = *(const bfx8*)(bc + o);
      a1l[f] = *(const bfx8*)(bc + 16384 + o);
    }
    if (i == 30) asm volatile("s_waitcnt vmcnt(0)" ::: "memory");
    __builtin_amdgcn_s_barrier();
    __builtin_amdgcn_s_setprio(1);
    #pragma unroll
    for (int f = 0; f < 2; ++f)
      #pragma unroll
      for (int nf = 0; nf < 4; ++nf) {
        acc[2+f][nf] = mfma16(a1l[f], bh[nf], acc[2+f][nf]);
        acc[2+f][nf] = mfma16(a1h[f], bl[nf], acc[2+f][nf]);
        acc[2+f][nf] = mfma16(a1h[f], bh[nf], acc[2+f][nf]);
      }
    __builtin_amdgcn_s_setprio(0);
    __builtin_amdgcn_s_barrier();
    sl = (sl == 2) ? 0 : sl + 1;
  }

  // ---- epilogue: C/D layout col=lane&15, row=4*(lane>>4)+reg ----
  #pragma unroll
  for (int mf = 0; mf < 4; ++mf)
    #pragma unroll
    for (int nf = 0; nf < 4; ++nf)
      #pragma unroll
      for (int rg = 0; rg < 4; ++rg) {
        const int gr = m0 + wm*64 + mf*16 + 4*l4 + rg;
        const int gc = n0 + wn*64 + nf*16 + l15;
        float v = acc[mf][nf][rg];
        if (EPI == 1) {
          v += (gc < CH) ? biasA[gc] : ((gc >= 2*CH) ? biasB[gc - 2*CH] : 0.f);
          const int which = gc >> 10, cc = gc & (CH-1);
          const int hh = cc >> 6, dd = cc & 63;
          const int bb = gr >> 11, ll = gr & (SEQ-1);
          if (which < 2)
            outQ[(size_t)which*BHLD + ((size_t)((bb*NH + hh)*SEQ) + ll)*DD + dd] = (__bf16)v;
          else
            outV[((size_t)(bb*NH + hh)*DD + dd)*SEQ + ll] = (__bf16)v;
        } else {
          outF[(size_t)gr*CH + gc] = v + biasA[gc];
        }
      }
}

// --------------------------- l2 normalize q,k (in place) --------------------
__global__ __launch_bounds__(256) void norml2(__bf16* __restrict__ qk,
                                              const float* __restrict__ scale_mul) {
  const int tid = threadIdx.x;
  const int rid = blockIdx.x * 32 + (tid >> 3);
  const int e0 = (tid & 7) * 8;
  const int r = rid & (131072 - 1);
  const bool isq = rid < 131072;
  const int hh = (r >> 11) & 15;
  float sm = 1.f;
  if (isq) sm = __expf(fminf(scale_mul[hh], 4.605170185988091f));
  __bf16* p = qk + (size_t)rid * DD + e0;
  bfx8 v = *(bfx8*)p;
  float f[8]; float ss = 0.f;
  #pragma unroll
  for (int j = 0; j < 8; ++j) { f[j] = (float)v[j]; ss += f[j]*f[j]; }
  ss += __shfl_xor(ss, 1); ss += __shfl_xor(ss, 2); ss += __shfl_xor(ss, 4);
  const float sc = sm / fmaxf(sqrtf(ss), 1e-12f);
  #pragma unroll
  for (int j = 0; j < 8; ++j) v[j] = (__bf16)(f[j] * sc);
  *(bfx8*)p = v;
}

// --------------------------- flash attention (bf16, swapped ops) ------------
__global__ __launch_bounds__(256, 2) void attn_kernel(
    const __bf16* __restrict__ qn, const __bf16* __restrict__ kn,
    const __bf16* __restrict__ vtg,
    const float* __restrict__ bias, const int* __restrict__ flag,
    __bf16* __restrict__ ao_hi, __bf16* __restrict__ ao_lo)
{
  __shared__ alignas(16) char Ks[16384];
  __shared__ alignas(16) char Vt[16384];
  __shared__ alignas(16) char Ps[32768];

  const int tid = threadIdx.x, lane = tid & 63, w = tid >> 6;
  const int l15 = lane & 15, l4 = lane >> 4;
  const int wk = (int)(blockIdx.x & 7) * 128 + (int)(blockIdx.x >> 3);
  const int qt = wk & 15, h = (wk >> 4) & 15, b = wk >> 8;
  const size_t bh = ((size_t)(b*NH + h)) * SEQ * DD;
  const int hasbias = *flag;
  char* Pw = Ps + w*8192;

  bfx8 Qf[2][2];
  const int q0 = qt*128 + w*32;
  #pragma unroll
  for (int mf = 0; mf < 2; ++mf)
    #pragma unroll
    for (int kd = 0; kd < 2; ++kd)
      Qf[mf][kd] = *(const bfx8*)(qn + bh + (size_t)(q0 + mf*16 + l15)*DD + kd*32 + l4*8);

  const f32x4 zz = {0.f, 0.f, 0.f, 0.f};
  f32x4 O[2][4];
  float m_[2] = {-1e30f, -1e30f}, l_[2] = {0.f, 0.f};
  #pragma unroll
  for (int mf = 0; mf < 2; ++mf)
    #pragma unroll
    for (int nd = 0; nd < 4; ++nd) O[mf][nd] = zz;

  for (int t = 0; t < 16; ++t) {
    __syncthreads();

    const __bf16* ksrc = kn + bh + (size_t)t*128*DD;
    #pragma unroll
    for (int i = 0; i < 4; ++i) {
      const int s = i*256 + tid;
      const int row = s >> 3;
      const int c = (s & 7) ^ (row & 7);
      async16(Ks + (size_t)(i*256 + w*64)*16, ksrc + (size_t)row*DD + c*8);
    }
    const __bf16* vsrc = vtg + bh + (size_t)t*128;
    #pragma unroll
    for (int i = 0; i < 4; ++i) {
      const int s = i*256 + tid;
      const int row = s >> 4;
      const int c = (s & 15) ^ (row & 15);
      async16(Vt + (size_t)(i*256 + w*64)*16, vsrc + (size_t)row*SEQ + c*8);
    }
    __syncthreads();

    // ---- S^T = K Q^T : lane holds q=l15(+16mf), k=16nf+4*l4+rg ----
    f32x4 ST[2][8];
    __builtin_amdgcn_s_setprio(1);
    #pragma unroll
    for (int nf = 0; nf < 8; ++nf) {
      const int r = nf*16 + l15;
      const bfx8 K0 = *(const bfx8*)(Ks + r*128 + ((l4 ^ (r & 7)) * 16));
      const bfx8 K1 = *(const bfx8*)(Ks + r*128 + (((4 + l4) ^ (r & 7)) * 16));
      #pragma unroll
      for (int mf = 0; mf < 2; ++mf) {
        f32x4 sacc = mfma16(K0, Qf[mf][0], zz);
        ST[mf][nf] = mfma16(K1, Qf[mf][1], sacc);
      }
    }
    __builtin_amdgcn_s_setprio(0);

    if (hasbias) {
      #pragma unroll
      for (int mf = 0; mf < 2; ++mf) {
        const size_t qg = (size_t)(q0 + mf*16 + l15);
        const float* bp = bias + qg*SEQ + (size_t)t*128;
        #pragma unroll
        for (int nf = 0; nf < 8; ++nf)
          #pragma unroll
          for (int rg = 0; rg < 4; ++rg)
            ST[mf][nf][rg] += bp[nf*16 + 4*l4 + rg];
      }
    }

    #pragma unroll
    for (int mf = 0; mf < 2; ++mf) {
      f32x4 mv = ST[mf][0];
      #pragma unroll
      for (int nf = 1; nf < 8; ++nf)
        #pragma unroll
        for (int rg = 0; rg < 4; ++rg) mv[rg] = fmaxf(mv[rg], ST[mf][nf][rg]);
      float mx = fmaxf(fmaxf(mv[0], mv[1]), fmaxf(mv[2], mv[3]));
      mx = fmaxf(mx, __shfl_xor(mx, 16));
      mx = fmaxf(mx, __shfl_xor(mx, 32));
      const float mn = fmaxf(m_[mf], mx);
      const float corr = __expf(m_[mf] - mn);
      f32x4 sv = zz;
      #pragma unroll
      for (int nf = 0; nf < 8; ++nf) {
        #pragma unroll
        for (int rg = 0; rg < 4; ++rg) {
          ST[mf][nf][rg] = __expf(ST[mf][nf][rg] - mn);
          sv[rg] += ST[mf][nf][rg];
        }
      }
      float rs = (sv[0] + sv[1]) + (sv[2] + sv[3]);
      rs += __shfl_xor(rs, 16);
      rs += __shfl_xor(rs, 32);
      l_[mf] = l_[mf] * corr + rs;
      m_[mf] = mn;
      #pragma unroll
      for (int nd = 0; nd < 4; ++nd)
        #pragma unroll
        for (int rg = 0; rg < 4; ++rg) O[mf][nd][rg] *= corr;

      const int row = mf*16 + l15;
      #pragma unroll
      for (int nf = 0; nf < 8; ++nf) {
        bfx4 p4;
        #pragma unroll
        for (int rg = 0; rg < 4; ++rg) p4[rg] = (__bf16)ST[mf][nf][rg];
        const int cpos = (2*nf + (l4 >> 1)) ^ l15;
        *(bfx4*)(Pw + row*256 + cpos*16 + (l4 & 1)*8) = p4;
      }
    }

    __builtin_amdgcn_s_setprio(1);
    #pragma unroll
    for (int kk = 0; kk < 4; ++kk) {
      bfx8 Pf[2];
      #pragma unroll
      for (int mf = 0; mf < 2; ++mf)
        Pf[mf] = *(const bfx8*)(Pw + (mf*16 + l15)*256 + (((4*kk + l4) ^ l15) * 16));
      #pragma unroll
      for (int nd = 0; nd < 4; ++nd) {
        const bfx8 Vf = *(const bfx8*)(Vt + (nd*16 + l15)*256 + (((4*kk + l4) ^ l15) * 16));
        #pragma unroll
        for (int mf = 0; mf < 2; ++mf)
          O[mf][nd] = mfma16(Vf, Pf[mf], O[mf][nd]);
      }
    }
    __builtin_amdgcn_s_setprio(0);
  }

  #pragma unroll
  for (int mf = 0; mf < 2; ++mf) {
    const float inv = 1.f / l_[mf];
    const int qg = q0 + mf*16 + l15;
    #pragma unroll
    for (int nd = 0; nd < 4; ++nd) {
      bfx4 hb, lb;
      #pragma unroll
      for (int rg = 0; rg < 4; ++rg) {
        const float v = O[mf][nd][rg] * inv;
        hb[rg] = (__bf16)v;
        lb[rg] = (__bf16)(v - (float)hb[rg]);
      }
      const size_t idx = ((size_t)(b*SEQ + qg))*CH + h*DD + nd*16 + 4*l4;
      *(bfx4*)(ao_hi + idx) = hb;
      *(bfx4*)(ao_lo + idx) = lb;
    }
  }
}

// ---------------------------------------------------------------------------
extern "C" void kernel_launch(void* const* d_in, const int* in_sizes, int n_in,
                              void* d_out, int out_size, void* d_ws, size_t ws_size,
                              hipStream_t stream) {
  const float* x         = (const float*)d_in[0];
  const float* attn_bias = (const float*)d_in[1];
  const float* qkv_w     = (const float*)d_in[2];
  const float* q_bias    = (const float*)d_in[3];
  const float* v_bias    = (const float*)d_in[4];
  const float* scale_mul = (const float*)d_in[5];
  const float* proj_w    = (const float*)d_in[6];
  const float* proj_b    = (const float*)d_in[7];
  float* out = (float*)d_out;

  char* ws = (char*)d_ws;
  size_t off = 0;
  auto alloc = [&](size_t n) { char* p = ws + off; off += (n + 255) & ~(size_t)255; return p; };
  __bf16* x_h  = (__bf16*)alloc((size_t)MROWS*CH*2);
  __bf16* x_l  = (__bf16*)alloc((size_t)MROWS*CH*2);
  __bf16* w_h  = (__bf16*)alloc((size_t)3*CH*CH*2);
  __bf16* w_l  = (__bf16*)alloc((size_t)3*CH*CH*2);
  __bf16* p_h  = (__bf16*)alloc((size_t)CH*CH*2);
  __bf16* p_l  = (__bf16*)alloc((size_t)CH*CH*2);
  __bf16* qkvn = (__bf16*)alloc((size_t)2*BHLD*2);   // q,k [B,H,L,D]
  __bf16* vt   = (__bf16*)alloc((size_t)BHLD*2);     // v   [B,H,D,L]
  __bf16* ao_h = (__bf16*)alloc((size_t)MROWS*CH*2);
  __bf16* ao_l = (__bf16*)alloc((size_t)MROWS*CH*2);
  int*    flag = (int*)alloc(256);

  (void)hipFuncSetAttribute(reinterpret_cast<const void*>(&gemmp<1>),
                            hipFuncAttributeMaxDynamicSharedMemorySize, 3*SLOT);
  (void)hipFuncSetAttribute(reinterpret_cast<const void*>(&gemmp<2>),
                            hipFuncAttributeMaxDynamicSharedMemorySize, 3*SLOT);

  split_kernel<<<MROWS*CH/4/256, 256, 0, stream>>>((const float4*)x, x_h, x_l, MROWS*CH/4);
  split_kernel<<<3*CH*CH/4/256, 256, 0, stream>>>((const float4*)qkv_w, w_h, w_l, 3*CH*CH/4);
  split_kernel<<<CH*CH/4/256, 256, 0, stream>>>((const float4*)proj_w, p_h, p_l, CH*CH/4);

  hipMemsetAsync(flag, 0, sizeof(int), stream);
  scan_nz<<<2048, 256, 0, stream>>>((const uint4*)attn_bias, SEQ*SEQ/4, flag);

  // GEMM1: [8192,3072] = x * qkv_w^T (+bias) -> q/k [B,H,L,D], v [B,H,D,L]
  gemmp<1><<<(MROWS/256)*(3*CH/128), 512, 3*SLOT, stream>>>(
      x_h, x_l, w_h, w_l, 3*CH/128, q_bias, v_bias, nullptr, qkvn, vt);

  norml2<<<2*NB*NH*SEQ/32, 256, 0, stream>>>(qkvn, scale_mul);

  attn_kernel<<<NB*NH*(SEQ/128), 256, 0, stream>>>(
      qkvn, qkvn + (size_t)BHLD, vt, attn_bias, flag, ao_h, ao_l);

  // GEMM2: d_out = attn_out * proj_w^T + proj_b
  gemmp<2><<<(MROWS/256)*(CH/128), 512, 3*SLOT, stream>>>(
      ao_h, ao_l, p_h, p_l, CH/128, proj_b, nullptr, out, nullptr, nullptr);
}

// Round 5
// 390.202 us; speedup vs baseline: 1.1048x; 1.0010x over previous
//
#include <hip/hip_runtime.h>
#include <cstdint>

// ---------------------------------------------------------------------------
// SelfAttention (QK-l2norm variant), MI355X/gfx950.
// R5: GEMMs -> R2's 128x128/4-wave geometry (2 blocks/CU) + T3-minimum
// 2-phase double-buffer: stage(t+1) early, one barrier/K-step, vmcnt(0)
// drain hidden under 16 ds_read + 48 MFMA. Attention: exp2-folded softmax
// (log2e in q scale), defer-rescale (THR=12 log2-units, __all-uniform).
// Projections: Markidis hi/lo bf16 split (3 MFMAs) ~ fp32-accurate.
// ---------------------------------------------------------------------------

typedef __bf16 bfx8 __attribute__((ext_vector_type(8)));
typedef __bf16 bfx4 __attribute__((ext_vector_type(4)));
typedef float  f32x4 __attribute__((ext_vector_type(4)));

#define NB   4
#define NH   16
#define SEQ  2048
#define CH   1024
#define DD   64
#define MROWS (NB*SEQ)             /* 8192 */
#define BHLD  (NB*NH*SEQ*DD)       /* 8388608 */
#define LOG2E 1.44269504088896340736f

__device__ __forceinline__ void async16(void* lds, const void* g) {
  __builtin_amdgcn_global_load_lds((const __attribute__((address_space(1))) void*)g,
                                   (__attribute__((address_space(3))) void*)lds, 16, 0, 0);
}
__device__ __forceinline__ f32x4 mfma16(bfx8 a, bfx8 b, f32x4 c) {
  return __builtin_amdgcn_mfma_f32_16x16x32_bf16(a, b, c, 0, 0, 0);
}

extern "C" __device__ float __ocml_exp2_f32(float);
__device__ __forceinline__ float fexp2(float x) {
#if __has_builtin(__builtin_amdgcn_exp2f)
  return __builtin_amdgcn_exp2f(x);
#else
  return __ocml_exp2_f32(x);
#endif
}

// --------------------------- hi/lo split (Markidis) -------------------------
__global__ __launch_bounds__(256) void split_kernel(const float4* __restrict__ src,
                                                    __bf16* __restrict__ hi,
                                                    __bf16* __restrict__ lo, int n4) {
  int i = blockIdx.x * 256 + threadIdx.x;
  if (i >= n4) return;
  float4 v = src[i];
  float vv[4] = {v.x, v.y, v.z, v.w};
  bfx4 h, l;
  #pragma unroll
  for (int j = 0; j < 4; ++j) {
    __bf16 hb = (__bf16)vv[j];
    h[j] = hb;
    l[j] = (__bf16)(vv[j] - (float)hb);
  }
  *(bfx4*)(hi + 4*(size_t)i) = h;
  *(bfx4*)(lo + 4*(size_t)i) = l;
}

// --------------------------- bias nonzero scan ------------------------------
__global__ __launch_bounds__(256) void scan_nz(const uint4* __restrict__ p, int n4,
                                               int* __restrict__ flag) {
  unsigned acc = 0;
  const int stride = gridDim.x * 256;
  for (int i = blockIdx.x * 256 + threadIdx.x; i < n4; i += stride) {
    uint4 u = p[i];
    acc |= (u.x | u.y | u.z | u.w) & 0x7fffffffu;
  }
  if (acc) atomicOr(flag, 1);
}

// ------------------- split-bf16 GEMM 128x128, 2-phase dbuf ------------------
// C[M,N] = A[M,K]*B[N,K]^T, hi/lo bf16 pairs. 4 waves (2x2 of 64x64), BK=32.
// LDS: 2 bufs x {Ah,Al,Bh,Bl}[128x32] = 65536 B -> 2 blocks/CU.
// Per K-step: {stage(t+1)->other buf; ds_read cur; 48 MFMA; vmcnt(0); barrier}.
// Single barrier per K-step; drain hidden under the reads+MFMA of tile t.
// EPI==1: +concat(q_bias,0,v_bias); q/k -> [B,H,L,D] bf16, v -> [B,H,D,L].
// EPI==2: +proj_b -> f32 out.
template<int EPI>
__global__ __launch_bounds__(256, 2) void gemmd(
    const __bf16* __restrict__ Agh, const __bf16* __restrict__ Agl,
    const __bf16* __restrict__ Bgh, const __bf16* __restrict__ Bgl,
    const int Ntiles, const int K,
    const float* __restrict__ biasA, const float* __restrict__ biasB,
    float* __restrict__ outF, __bf16* __restrict__ outQ, __bf16* __restrict__ outV)
{
  __shared__ alignas(16) char lds[65536];   // buf0 | buf1; each: Ah|Al|Bh|Bl 8KB
  const int tid = threadIdx.x;
  const int lane = tid & 63, w = tid >> 6;
  const int l15 = lane & 15, l4 = lane >> 4;
  const int nwg = (int)gridDim.x;
  const int wk = (int)(blockIdx.x & 7) * (nwg >> 3) + (int)(blockIdx.x >> 3); // nwg%8==0
  const int mt = wk / Ntiles, nt = wk % Ntiles;
  const int m0 = mt * 128, n0 = nt * 128;
  const int wm = (w >> 1) * 64, wn = (w & 1) * 64;

  const f32x4 zz = {0.f, 0.f, 0.f, 0.f};
  f32x4 acc[4][4];
  #pragma unroll
  for (int a = 0; a < 4; ++a)
    #pragma unroll
    for (int b = 0; b < 4; ++b) acc[a][b] = zz;

  // staging geometry: slot s = i*256+tid -> LDS byte s*16; row=s>>2,
  // logical k-chunk c = (s&3) ^ ((row>>1)&3)  (involution; read side matches)
  int st_row[2], st_c[2], st_lds[2];
  #pragma unroll
  for (int i = 0; i < 2; ++i) {
    const int s = i*256 + tid;
    st_row[i] = s >> 2;
    st_c[i]   = (s & 3) ^ ((st_row[i] >> 1) & 3);
    st_lds[i] = (i*256 + w*64) * 16;     // wave-uniform base; HW adds lane*16
  }

  auto stage = [&](int k0, char* bb) {
    #pragma unroll
    for (int i = 0; i < 2; ++i) {
      const size_t ga = (size_t)(m0 + st_row[i]) * K + (size_t)(k0 + st_c[i]*8);
      const size_t gb = (size_t)(n0 + st_row[i]) * K + (size_t)(k0 + st_c[i]*8);
      async16(bb +         st_lds[i], Agh + ga);
      async16(bb +  8192 + st_lds[i], Agl + ga);
      async16(bb + 16384 + st_lds[i], Bgh + gb);
      async16(bb + 24576 + st_lds[i], Bgl + gb);
    }
  };

  const int NT = K >> 5;
  stage(0, lds);
  asm volatile("s_waitcnt vmcnt(0)" ::: "memory");
  __builtin_amdgcn_s_barrier();

  #pragma unroll 1
  for (int t = 0; t < NT; ++t) {
    char* bc = lds + (t & 1) * 32768;
    if (t + 1 < NT) stage((t + 1) << 5, lds + ((t + 1) & 1) * 32768);

    bfx8 ah[4], al[4], bh[4], bl[4];
    #pragma unroll
    for (int f = 0; f < 4; ++f) {
      const int ra = wm + f*16 + l15;
      const int oa = ra*64 + ((l4 ^ ((ra >> 1) & 3)) * 16);
      ah[f] = *(const bfx8*)(bc + oa);
      al[f] = *(const bfx8*)(bc + 8192 + oa);
      const int rb = wn + f*16 + l15;
      const int ob = rb*64 + ((l4 ^ ((rb >> 1) & 3)) * 16);
      bh[f] = *(const bfx8*)(bc + 16384 + ob);
      bl[f] = *(const bfx8*)(bc + 24576 + ob);
    }
    __builtin_amdgcn_s_setprio(1);
    #pragma unroll
    for (int mf = 0; mf < 4; ++mf)
      #pragma unroll
      for (int nf = 0; nf < 4; ++nf) {
        acc[mf][nf] = mfma16(al[mf], bh[nf], acc[mf][nf]);
        acc[mf][nf] = mfma16(ah[mf], bl[nf], acc[mf][nf]);
        acc[mf][nf] = mfma16(ah[mf], bh[nf], acc[mf][nf]);
      }
    __builtin_amdgcn_s_setprio(0);
    asm volatile("s_waitcnt vmcnt(0)" ::: "memory");   // stage(t+1) landed
    __builtin_amdgcn_s_barrier();                      // all waves past reads of bc
  }

  // epilogue: C/D layout col=lane&15, row=4*(lane>>4)+reg
  #pragma unroll
  for (int mf = 0; mf < 4; ++mf)
    #pragma unroll
    for (int nf = 0; nf < 4; ++nf)
      #pragma unroll
      for (int rg = 0; rg < 4; ++rg) {
        const int gr = m0 + wm + mf*16 + 4*l4 + rg;
        const int gc = n0 + wn + nf*16 + l15;
        float v = acc[mf][nf][rg];
        if (EPI == 1) {
          v += (gc < CH) ? biasA[gc] : ((gc >= 2*CH) ? biasB[gc - 2*CH] : 0.f);
          const int which = gc >> 10, cc = gc & (CH-1);
          const int hh = cc >> 6, dd = cc & 63;
          const int bb = gr >> 11, ll = gr & (SEQ-1);
          if (which < 2)
            outQ[(size_t)which*BHLD + ((size_t)((bb*NH + hh)*SEQ) + ll)*DD + dd] = (__bf16)v;
          else
            outV[((size_t)(bb*NH + hh)*DD + dd)*SEQ + ll] = (__bf16)v;
        } else {
          outF[(size_t)gr*CH + gc] = v + biasA[gc];
        }
      }
}

// --------------------------- l2 normalize q,k (in place) --------------------
// q additionally scaled by exp(min(scale_mul,log100)) * log2(e)  (exp2 fold)
__global__ __launch_bounds__(256) void norml2(__bf16* __restrict__ qk,
                                              const float* __restrict__ scale_mul) {
  const int tid = threadIdx.x;
  const int rid = blockIdx.x * 32 + (tid >> 3);
  const int e0 = (tid & 7) * 8;
  const int r = rid & (131072 - 1);
  const bool isq = rid < 131072;
  const int hh = (r >> 11) & 15;
  float sm = 1.f;
  if (isq) sm = __expf(fminf(scale_mul[hh], 4.605170185988091f)) * LOG2E;
  __bf16* p = qk + (size_t)rid * DD + e0;
  bfx8 v = *(bfx8*)p;
  float f[8]; float ss = 0.f;
  #pragma unroll
  for (int j = 0; j < 8; ++j) { f[j] = (float)v[j]; ss += f[j]*f[j]; }
  ss += __shfl_xor(ss, 1); ss += __shfl_xor(ss, 2); ss += __shfl_xor(ss, 4);
  const float sc = sm / fmaxf(sqrtf(ss), 1e-12f);
  #pragma unroll
  for (int j = 0; j < 8; ++j) v[j] = (__bf16)(f[j] * sc);
  *(bfx8*)p = v;
}

// --------------------------- flash attention (bf16, swapped ops) ------------
// Scores are in log2-units (log2e folded into q). Softmax uses raw v_exp_f32.
// Defer-rescale: skip corr/O-rescale while __all(mx - m <= 12) (bounded 2^12).
__global__ __launch_bounds__(256, 2) void attn_kernel(
    const __bf16* __restrict__ qn, const __bf16* __restrict__ kn,
    const __bf16* __restrict__ vtg,
    const float* __restrict__ bias, const int* __restrict__ flag,
    __bf16* __restrict__ ao_hi, __bf16* __restrict__ ao_lo)
{
  __shared__ alignas(16) char Ks[16384];
  __shared__ alignas(16) char Vt[16384];
  __shared__ alignas(16) char Ps[32768];

  const int tid = threadIdx.x, lane = tid & 63, w = tid >> 6;
  const int l15 = lane & 15, l4 = lane >> 4;
  const int wk = (int)(blockIdx.x & 7) * 128 + (int)(blockIdx.x >> 3);
  const int qt = wk & 15, h = (wk >> 4) & 15, b = wk >> 8;
  const size_t bh = ((size_t)(b*NH + h)) * SEQ * DD;
  const int hasbias = *flag;
  char* Pw = Ps + w*8192;

  bfx8 Qf[2][2];
  const int q0 = qt*128 + w*32;
  #pragma unroll
  for (int mf = 0; mf < 2; ++mf)
    #pragma unroll
    for (int kd = 0; kd < 2; ++kd)
      Qf[mf][kd] = *(const bfx8*)(qn + bh + (size_t)(q0 + mf*16 + l15)*DD + kd*32 + l4*8);

  const f32x4 zz = {0.f, 0.f, 0.f, 0.f};
  f32x4 O[2][4];
  float m_[2] = {-1e30f, -1e30f}, l_[2] = {0.f, 0.f};
  #pragma unroll
  for (int mf = 0; mf < 2; ++mf)
    #pragma unroll
    for (int nd = 0; nd < 4; ++nd) O[mf][nd] = zz;

  for (int t = 0; t < 16; ++t) {
    __syncthreads();

    const __bf16* ksrc = kn + bh + (size_t)t*128*DD;
    #pragma unroll
    for (int i = 0; i < 4; ++i) {
      const int s = i*256 + tid;
      const int row = s >> 3;
      const int c = (s & 7) ^ (row & 7);
      async16(Ks + (size_t)(i*256 + w*64)*16, ksrc + (size_t)row*DD + c*8);
    }
    const __bf16* vsrc = vtg + bh + (size_t)t*128;
    #pragma unroll
    for (int i = 0; i < 4; ++i) {
      const int s = i*256 + tid;
      const int row = s >> 4;
      const int c = (s & 15) ^ (row & 15);
      async16(Vt + (size_t)(i*256 + w*64)*16, vsrc + (size_t)row*SEQ + c*8);
    }
    __syncthreads();

    // ---- S^T = K Q^T : lane holds q=l15(+16mf), k=16nf+4*l4+rg ----
    f32x4 ST[2][8];
    __builtin_amdgcn_s_setprio(1);
    #pragma unroll
    for (int nf = 0; nf < 8; ++nf) {
      const int r = nf*16 + l15;
      const bfx8 K0 = *(const bfx8*)(Ks + r*128 + ((l4 ^ (r & 7)) * 16));
      const bfx8 K1 = *(const bfx8*)(Ks + r*128 + (((4 + l4) ^ (r & 7)) * 16));
      #pragma unroll
      for (int mf = 0; mf < 2; ++mf) {
        f32x4 sacc = mfma16(K0, Qf[mf][0], zz);
        ST[mf][nf] = mfma16(K1, Qf[mf][1], sacc);
      }
    }
    __builtin_amdgcn_s_setprio(0);

    if (hasbias) {
      #pragma unroll
      for (int mf = 0; mf < 2; ++mf) {
        const size_t qg = (size_t)(q0 + mf*16 + l15);
        const float* bp = bias + qg*SEQ + (size_t)t*128;
        #pragma unroll
        for (int nf = 0; nf < 8; ++nf)
          #pragma unroll
          for (int rg = 0; rg < 4; ++rg)
            ST[mf][nf][rg] += bp[nf*16 + 4*l4 + rg] * LOG2E;
      }
    }

    // ---- online softmax (log2-units; defer-rescale) ----
    #pragma unroll
    for (int mf = 0; mf < 2; ++mf) {
      f32x4 mv = ST[mf][0];
      #pragma unroll
      for (int nf = 1; nf < 8; ++nf)
        #pragma unroll
        for (int rg = 0; rg < 4; ++rg) mv[rg] = fmaxf(mv[rg], ST[mf][nf][rg]);
      float mx = fmaxf(fmaxf(mv[0], mv[1]), fmaxf(mv[2], mv[3]));
      mx = fmaxf(mx, __shfl_xor(mx, 16));
      mx = fmaxf(mx, __shfl_xor(mx, 32));
      const bool skip = __all(mx - m_[mf] <= 12.0f) != 0;
      const float mn = skip ? m_[mf] : fmaxf(m_[mf], mx);
      f32x4 sv = zz;
      #pragma unroll
      for (int nf = 0; nf < 8; ++nf) {
        #pragma unroll
        for (int rg = 0; rg < 4; ++rg) {
          const float pv = fexp2(ST[mf][nf][rg] - mn);
          ST[mf][nf][rg] = pv;
          sv[rg] += pv;
        }
      }
      float rs = (sv[0] + sv[1]) + (sv[2] + sv[3]);
      rs += __shfl_xor(rs, 16);
      rs += __shfl_xor(rs, 32);
      if (skip) {
        l_[mf] += rs;
      } else {
        const float corr = fexp2(m_[mf] - mn);
        l_[mf] = l_[mf] * corr + rs;
        m_[mf] = mn;
        #pragma unroll
        for (int nd = 0; nd < 4; ++nd)
          #pragma unroll
          for (int rg = 0; rg < 4; ++rg) O[mf][nd][rg] *= corr;
      }

      // ---- P -> Ps[q=32][k=128] per wave, b64 swizzled writes ----
      const int row = mf*16 + l15;
      #pragma unroll
      for (int nf = 0; nf < 8; ++nf) {
        bfx4 p4;
        #pragma unroll
        for (int rg = 0; rg < 4; ++rg) p4[rg] = (__bf16)ST[mf][nf][rg];
        const int cpos = (2*nf + (l4 >> 1)) ^ l15;
        *(bfx4*)(Pw + row*256 + cpos*16 + (l4 & 1)*8) = p4;
      }
    }

    // ---- O^T += V^T P : lane holds q=l15(+16mf), d=16nd+4*l4+rg ----
    __builtin_amdgcn_s_setprio(1);
    #pragma unroll
    for (int kk = 0; kk < 4; ++kk) {
      bfx8 Pf[2];
      #pragma unroll
      for (int mf = 0; mf < 2; ++mf)
        Pf[mf] = *(const bfx8*)(Pw + (mf*16 + l15)*256 + (((4*kk + l4) ^ l15) * 16));
      #pragma unroll
      for (int nd = 0; nd < 4; ++nd) {
        const bfx8 Vf = *(const bfx8*)(Vt + (nd*16 + l15)*256 + (((4*kk + l4) ^ l15) * 16));
        #pragma unroll
        for (int mf = 0; mf < 2; ++mf)
          O[mf][nd] = mfma16(Vf, Pf[mf], O[mf][nd]);
      }
    }
    __builtin_amdgcn_s_setprio(0);
  }

  #pragma unroll
  for (int mf = 0; mf < 2; ++mf) {
    const float inv = 1.f / l_[mf];
    const int qg = q0 + mf*16 + l15;
    #pragma unroll
    for (int nd = 0; nd < 4; ++nd) {
      bfx4 hb, lb;
      #pragma unroll
      for (int rg = 0; rg < 4; ++rg) {
        const float v = O[mf][nd][rg] * inv;
        hb[rg] = (__bf16)v;
        lb[rg] = (__bf16)(v - (float)hb[rg]);
      }
      const size_t idx = ((size_t)(b*SEQ + qg))*CH + h*DD + nd*16 + 4*l4;
      *(bfx4*)(ao_hi + idx) = hb;
      *(bfx4*)(ao_lo + idx) = lb;
    }
  }
}

// ---------------------------------------------------------------------------
extern "C" void kernel_launch(void* const* d_in, const int* in_sizes, int n_in,
                              void* d_out, int out_size, void* d_ws, size_t ws_size,
                              hipStream_t stream) {
  const float* x         = (const float*)d_in[0];
  const float* attn_bias = (const float*)d_in[1];
  const float* qkv_w     = (const float*)d_in[2];
  const float* q_bias    = (const float*)d_in[3];
  const float* v_bias    = (const float*)d_in[4];
  const float* scale_mul = (const float*)d_in[5];
  const float* proj_w    = (const float*)d_in[6];
  const float* proj_b    = (const float*)d_in[7];
  float* out = (float*)d_out;

  char* ws = (char*)d_ws;
  size_t off = 0;
  auto alloc = [&](size_t n) { char* p = ws + off; off += (n + 255) & ~(size_t)255; return p; };
  __bf16* x_h  = (__bf16*)alloc((size_t)MROWS*CH*2);
  __bf16* x_l  = (__bf16*)alloc((size_t)MROWS*CH*2);
  __bf16* w_h  = (__bf16*)alloc((size_t)3*CH*CH*2);
  __bf16* w_l  = (__bf16*)alloc((size_t)3*CH*CH*2);
  __bf16* p_h  = (__bf16*)alloc((size_t)CH*CH*2);
  __bf16* p_l  = (__bf16*)alloc((size_t)CH*CH*2);
  __bf16* qkvn = (__bf16*)alloc((size_t)2*BHLD*2);   // q,k [B,H,L,D]
  __bf16* vt   = (__bf16*)alloc((size_t)BHLD*2);     // v   [B,H,D,L]
  __bf16* ao_h = (__bf16*)alloc((size_t)MROWS*CH*2);
  __bf16* ao_l = (__bf16*)alloc((size_t)MROWS*CH*2);
  int*    flag = (int*)alloc(256);

  split_kernel<<<MROWS*CH/4/256, 256, 0, stream>>>((const float4*)x, x_h, x_l, MROWS*CH/4);
  split_kernel<<<3*CH*CH/4/256, 256, 0, stream>>>((const float4*)qkv_w, w_h, w_l, 3*CH*CH/4);
  split_kernel<<<CH*CH/4/256, 256, 0, stream>>>((const float4*)proj_w, p_h, p_l, CH*CH/4);

  hipMemsetAsync(flag, 0, sizeof(int), stream);
  scan_nz<<<2048, 256, 0, stream>>>((const uint4*)attn_bias, SEQ*SEQ/4, flag);

  // GEMM1: [8192,3072] = x * qkv_w^T (+bias) -> q/k [B,H,L,D], v [B,H,D,L]
  gemmd<1><<<(MROWS/128)*(3*CH/128), 256, 0, stream>>>(
      x_h, x_l, w_h, w_l, 3*CH/128, CH, q_bias, v_bias, nullptr, qkvn, vt);

  norml2<<<2*NB*NH*SEQ/32, 256, 0, stream>>>(qkvn, scale_mul);

  attn_kernel<<<NB*NH*(SEQ/128), 256, 0, stream>>>(
      qkvn, qkvn + (size_t)BHLD, vt, attn_bias, flag, ao_h, ao_l);

  // GEMM2: d_out = attn_out * proj_w^T + proj_b
  gemmd<2><<<(MROWS/128)*(CH/128), 256, 0, stream>>>(
      ao_h, ao_l, p_h, p_l, CH/128, CH, proj_b, nullptr, out, nullptr, nullptr);
}